// Round 7
// baseline (228.955 us; speedup 1.0000x reference)
//
#include <hip/hip_runtime.h>
#include <stdint.h>

// TriXTile: out = (relu((x @ sign(up_w)^T) * up_scale) @ sign(down_w)^T) * down_scale * out_scale
// Round 7: i8 path, B (weights) pre-arranged in MFMA-fragment-major order by
// the prepass and loaded global->reg (no LDS for B). A-only LDS (32KB/block),
// 128x128 tiles, 4 waves, 3 blocks/CU. One barrier per K-tile.

#define M_TOK 4096
#define DM 2048
#define DH 8192

typedef __attribute__((ext_vector_type(4))) int i32x4;
typedef __attribute__((ext_vector_type(8))) unsigned short u16x8;

__device__ __forceinline__ ushort f2bf_rne(float f) {
  union { float f; uint32_t u; } c; c.f = f;
  uint32_t u = c.u;
  uint32_t r = (u + 0x7FFFu + ((u >> 16) & 1u)) >> 16;
  return (ushort)r;
}

__device__ __forceinline__ float bf2f(ushort u) {
  union { uint32_t u; float f; } c; c.u = (uint32_t)u << 16;
  return c.f;
}

#define GLD16(g, l)                                                     \
  __builtin_amdgcn_global_load_lds(                                     \
      (const __attribute__((address_space(1))) void*)(g),               \
      (__attribute__((address_space(3))) void*)(l), 16, 0, 0)

#define FENCE() asm volatile("" ::: "memory")

// ---- quantize x: one block per row; row absmax -> sx[row]; i8 out ----
__global__ __launch_bounds__(256) void quantx_kernel(
    const float* __restrict__ x, int8_t* __restrict__ xq,
    float* __restrict__ sx) {
  const int row = blockIdx.x, tid = threadIdx.x;
  const float4* xr = (const float4*)(x + (size_t)row * 2048);
  float4 a = xr[tid * 2], b = xr[tid * 2 + 1];
  float m = fmaxf(fmaxf(fmaxf(fabsf(a.x), fabsf(a.y)), fmaxf(fabsf(a.z), fabsf(a.w))),
                  fmaxf(fmaxf(fabsf(b.x), fabsf(b.y)), fmaxf(fabsf(b.z), fabsf(b.w))));
#pragma unroll
  for (int off = 32; off >= 1; off >>= 1) m = fmaxf(m, __shfl_xor(m, off));
  __shared__ float red[4];
  if ((tid & 63) == 0) red[tid >> 6] = m;
  __syncthreads();
  m = fmaxf(fmaxf(red[0], red[1]), fmaxf(red[2], red[3]));
  const float inv = m > 0.f ? 127.f / m : 0.f;
  if (tid == 0) sx[row] = m > 0.f ? m / 127.f : 0.f;
  auto q8 = [&](float v) -> uint32_t {
    float q = rintf(v * inv);
    q = fminf(fmaxf(q, -127.f), 127.f);
    return (uint32_t)(uint8_t)(int8_t)(int)q;
  };
  uint32_t w0 = q8(a.x) | (q8(a.y) << 8) | (q8(a.z) << 16) | (q8(a.w) << 24);
  uint32_t w1 = q8(b.x) | (q8(b.y) << 8) | (q8(b.z) << 16) | (q8(b.w) << 24);
  uint32_t* o = (uint32_t*)(xq + (size_t)row * 2048);
  o[tid * 2] = w0;
  o[tid * 2 + 1] = w1;
}

// ---- sign(W) -> i8 in MFMA-fragment-major layout ----
// Chunk (cb,t) = 16KB covering W rows [cb*128,+128) x k [t*128,+128).
// chunk byte c*16 (c = ((wn*2+ks)*4+fc)*64 + lane):
//   sign(W[cb*128 + wn*64 + fc*16 + (lane&15)][t*128 + ks*64 + (lane>>4)*16 .. +16])
// grid = (R/128)*(Kd/128) blocks; bid = cb*nt + t.
__global__ __launch_bounds__(256) void signfrag_kernel(
    const float* __restrict__ W, int8_t* __restrict__ Bp, int Kd, int nt) {
  const int bid = blockIdx.x;
  const int cb = bid / nt, t = bid % nt;
  const int tid = threadIdx.x;
  int8_t* dst0 = Bp + ((size_t)bid << 14);
  auto s8 = [](float v) -> uint32_t {
    int s = (v > 0.f) - (v < 0.f);
    return (uint32_t)(uint8_t)(int8_t)s;
  };
#pragma unroll
  for (int i = 0; i < 4; ++i) {
    int c = tid + 256 * i;
    int l = c & 63, fc = (c >> 6) & 3, ks = (c >> 8) & 1, wn = c >> 9;
    int row = cb * 128 + wn * 64 + fc * 16 + (l & 15);
    int kb = t * 128 + ks * 64 + ((l >> 4) << 4);
    const float4* src = (const float4*)(W + (size_t)row * Kd + kb);
    uint32_t w[4];
#pragma unroll
    for (int j = 0; j < 4; ++j) {
      float4 v = src[j];
      w[j] = s8(v.x) | (s8(v.y) << 8) | (s8(v.z) << 16) | (s8(v.w) << 24);
    }
    *(uint4*)(dst0 + (size_t)c * 16) = make_uint4(w[0], w[1], w[2], w[3]);
  }
}

// ---- quantize hidden (bf16): row absmax -> sh[row]; i8 ----
__global__ __launch_bounds__(256) void quanth_kernel(
    const ushort* __restrict__ hid, int8_t* __restrict__ hq,
    float* __restrict__ sh) {
  const int row = blockIdx.x, tid = threadIdx.x;
  const u16x8* hr = (const u16x8*)(hid + (size_t)row * 8192);
  u16x8 h[4];
  float m = 0.f;
#pragma unroll
  for (int s = 0; s < 4; ++s) {
    h[s] = hr[tid * 4 + s];
#pragma unroll
    for (int j = 0; j < 8; ++j) m = fmaxf(m, fabsf(bf2f(h[s][j])));
  }
#pragma unroll
  for (int off = 32; off >= 1; off >>= 1) m = fmaxf(m, __shfl_xor(m, off));
  __shared__ float red[4];
  if ((tid & 63) == 0) red[tid >> 6] = m;
  __syncthreads();
  m = fmaxf(fmaxf(red[0], red[1]), fmaxf(red[2], red[3]));
  const float inv = m > 0.f ? 127.f / m : 0.f;
  if (tid == 0) sh[row] = m > 0.f ? m / 127.f : 0.f;
  auto q8 = [&](float v) -> uint32_t {
    float q = rintf(v * inv);
    q = fminf(fmaxf(q, -127.f), 127.f);
    return (uint32_t)(uint8_t)(int8_t)(int)q;
  };
  uint32_t* o = (uint32_t*)(hq + (size_t)row * 8192);
#pragma unroll
  for (int s = 0; s < 4; ++s) {
    uint32_t w0 = q8(bf2f(h[s][0])) | (q8(bf2f(h[s][1])) << 8) |
                  (q8(bf2f(h[s][2])) << 16) | (q8(bf2f(h[s][3])) << 24);
    uint32_t w1 = q8(bf2f(h[s][4])) | (q8(bf2f(h[s][5])) << 8) |
                  (q8(bf2f(h[s][6])) << 16) | (q8(bf2f(h[s][7])) << 24);
    o[tid * 8 + s * 2] = w0;
    o[tid * 8 + s * 2 + 1] = w1;
  }
}

// ---------------- unified 128x128 i8 GEMM, B fragment-direct ----------------
// C[M,N] = (A[M,K]i8 @ signW^T) scaled. 256 thr = 4 waves (2x2), 64x64/wave.
// A: LDS double-buffer 2x16KB (XOR-swizzled via pre-swizzled source).
// B: frag-major global chunks (bn,t) of 16KB, loaded to regs (8x dwordx4).
// Schedule/tile: [B-loads(8)] [ds_read 2 groups] [A-stage(t+1) 4 units]
// [vmcnt(4) retire B] [lgkm(4)+MFMA ks0] [lgkm(0)+MFMA ks1] [vmcnt(0)+barrier].
// EPI==0: C bf16 = relu(acc*rs[row]*cs[col]); EPI==1: C f32 = acc*rs*cs*os.
template <int EPI>
__global__ __launch_bounds__(256, 3) void gemm_bd_kernel(
    const int8_t* __restrict__ A, const int8_t* __restrict__ Bp,
    void* __restrict__ Cv, const float* __restrict__ rs,
    const float* __restrict__ cs, const float* __restrict__ os,
    int M, int N, int K) {
  constexpr int TILEA = 128 * 128;      // 16KB
  __shared__ __align__(16) char smem[2 * TILEA];

  const int nbn = N >> 7;
  const int bid = blockIdx.x;
  const int cpx = gridDim.x >> 3;       // grid % 8 == 0
  const int swz = (bid & 7) * cpx + (bid >> 3);
  const int bm = swz / nbn, bn = swz % nbn;

  const int tid = threadIdx.x;
  const int lane = tid & 63;
  const int wv = tid >> 6;
  const int wm = wv >> 1, wn = wv & 1;  // 2x2 waves, 64x64 each
  const int lr = lane & 15, lg = lane >> 4;

  // A staging: unit u covers rows u*32 + (tid>>3); 8 thr x 16B = 128B/row.
  const int srow = tid >> 3;
  const int scolB = ((tid & 7) ^ (srow & 7)) << 4;   // pre-swizzled source col
  const int8_t* aS = A + (size_t)(bm * 128 + srow) * K + scolB;
  const int ldsl = wv * 1024;
  const int nt = K >> 7;

  auto ASTAGE = [&](int t) {
    char* dst = smem + ((t & 1) ? TILEA : 0) + ldsl;
    const int8_t* src = aS + (size_t)t * 128;
#pragma unroll
    for (int u = 0; u < 4; ++u)
      GLD16(src + (size_t)(u * 32) * K, dst + u * 4096);
  };

  i32x4 acc[4][4] = {};

  // Prologue: tile 0 staged, published.
  ASTAGE(0);
  asm volatile("s_waitcnt vmcnt(0)" ::: "memory");
  __builtin_amdgcn_s_barrier();

  const int xorv = (lr & 7) << 4;
  const int k0 = (lg << 4) ^ xorv;
  const int k1 = (64 + (lg << 4)) ^ xorv;
  const int abase = (wm * 64 + lr) * 128;
  const size_t bwave = (size_t)((wn * 2) * 4) * 1024 + (size_t)lane * 16;

  for (int t = 0; t < nt; ++t) {
    // 1. B fragment loads (global, frag-major chunk for (bn, t))
    const int8_t* bTile = Bp + (((size_t)bn * nt + t) << 14);
    i32x4 b0[4], b1[4];
#pragma unroll
    for (int fc = 0; fc < 4; ++fc) {
      b0[fc] = *(const i32x4*)(bTile + bwave + (size_t)fc * 1024);
      b1[fc] = *(const i32x4*)(bTile + bwave + 4096 + (size_t)fc * 1024);
    }
    FENCE();

    // 2. ds_read A frags, two fenced groups (ks0, ks1)
    const char* bA = smem + ((t & 1) ? TILEA : 0) + abase;
    i32x4 a0[4], a1[4];
#pragma unroll
    for (int fr = 0; fr < 4; ++fr) a0[fr] = *(const i32x4*)(bA + fr * 2048 + k0);
    FENCE();
#pragma unroll
    for (int fr = 0; fr < 4; ++fr) a1[fr] = *(const i32x4*)(bA + fr * 2048 + k1);
    FENCE();

    // 3. stage A(t+1) into other buffer (its readers finished at prev barrier)
    if (t + 1 < nt) ASTAGE(t + 1);

    // 4. retire B loads (A stages are the 4 newest VMEM ops)
    if (t + 1 < nt) {
      asm volatile("s_waitcnt vmcnt(4)" ::: "memory");
    } else {
      asm volatile("s_waitcnt vmcnt(0)" ::: "memory");
    }
    __builtin_amdgcn_sched_barrier(0);

    // 5. ks0 MFMAs (a-group ks0 done at lgkm 4)
    asm volatile("s_waitcnt lgkmcnt(4)" ::: "memory");
    __builtin_amdgcn_sched_barrier(0);
    __builtin_amdgcn_s_setprio(1);
#pragma unroll
    for (int fr = 0; fr < 4; ++fr)
#pragma unroll
      for (int fc = 0; fc < 4; ++fc)
        acc[fr][fc] = __builtin_amdgcn_mfma_i32_16x16x64_i8(
            a0[fr], b0[fc], acc[fr][fc], 0, 0, 0);
    __builtin_amdgcn_s_setprio(0);

    // 6. ks1 MFMAs
    asm volatile("s_waitcnt lgkmcnt(0)" ::: "memory");
    __builtin_amdgcn_sched_barrier(0);
    __builtin_amdgcn_s_setprio(1);
#pragma unroll
    for (int fr = 0; fr < 4; ++fr)
#pragma unroll
      for (int fc = 0; fc < 4; ++fc)
        acc[fr][fc] = __builtin_amdgcn_mfma_i32_16x16x64_i8(
            a1[fr], b1[fc], acc[fr][fc], 0, 0, 0);
    __builtin_amdgcn_s_setprio(0);

    // 7. publish A(t+1)
    if (t + 1 < nt) {
      asm volatile("s_waitcnt vmcnt(0)" ::: "memory");
      __builtin_amdgcn_s_barrier();
    }
  }

  // Epilogue. C/D layout: col = lane&15, row = (lane>>4)*4 + reg.
  if (EPI == 0) {
    ushort* C = (ushort*)Cv;
    float cc[4];
#pragma unroll
    for (int fc = 0; fc < 4; ++fc) cc[fc] = cs[bn * 128 + wn * 64 + fc * 16 + lr];
#pragma unroll
    for (int fr = 0; fr < 4; ++fr) {
      int gr = bm * 128 + wm * 64 + fr * 16 + lg * 4;
      float4 rv = *(const float4*)(rs + gr);
#pragma unroll
      for (int fc = 0; fc < 4; ++fc) {
        int gcol = bn * 128 + wn * 64 + fc * 16 + lr;
        float v0 = (float)acc[fr][fc][0] * rv.x * cc[fc];
        float v1 = (float)acc[fr][fc][1] * rv.y * cc[fc];
        float v2 = (float)acc[fr][fc][2] * rv.z * cc[fc];
        float v3 = (float)acc[fr][fc][3] * rv.w * cc[fc];
        C[(size_t)(gr + 0) * N + gcol] = f2bf_rne(v0 > 0.f ? v0 : 0.f);
        C[(size_t)(gr + 1) * N + gcol] = f2bf_rne(v1 > 0.f ? v1 : 0.f);
        C[(size_t)(gr + 2) * N + gcol] = f2bf_rne(v2 > 0.f ? v2 : 0.f);
        C[(size_t)(gr + 3) * N + gcol] = f2bf_rne(v3 > 0.f ? v3 : 0.f);
      }
    }
  } else {
    float* C = (float*)Cv;
    float osv = os[0];
    float cc[4];
#pragma unroll
    for (int fc = 0; fc < 4; ++fc)
      cc[fc] = cs[bn * 128 + wn * 64 + fc * 16 + lr] * osv;
#pragma unroll
    for (int fr = 0; fr < 4; ++fr) {
      int gr = bm * 128 + wm * 64 + fr * 16 + lg * 4;
      float4 rv = *(const float4*)(rs + gr);
#pragma unroll
      for (int fc = 0; fc < 4; ++fc) {
        int gcol = bn * 128 + wn * 64 + fc * 16 + lr;
        C[(size_t)(gr + 0) * N + gcol] = (float)acc[fr][fc][0] * rv.x * cc[fc];
        C[(size_t)(gr + 1) * N + gcol] = (float)acc[fr][fc][1] * rv.y * cc[fc];
        C[(size_t)(gr + 2) * N + gcol] = (float)acc[fr][fc][2] * rv.z * cc[fc];
        C[(size_t)(gr + 3) * N + gcol] = (float)acc[fr][fc][3] * rv.w * cc[fc];
      }
    }
  }
}

extern "C" void kernel_launch(void* const* d_in, const int* in_sizes, int n_in,
                              void* d_out, int out_size, void* d_ws,
                              size_t ws_size, hipStream_t stream) {
  const float* x   = (const float*)d_in[0];
  const float* upw = (const float*)d_in[1];
  const float* dnw = (const float*)d_in[2];
  const float* ups = (const float*)d_in[3];
  const float* dns = (const float*)d_in[4];
  const float* osc = (const float*)d_in[5];
  float* out = (float*)d_out;

  char* ws = (char*)d_ws;
  int8_t* xq  = (int8_t*)(ws);              //  8 MB [4096][2048]
  int8_t* upb = (int8_t*)(ws + 8388608);    // 16 MB frag-major (64 cb x 16 t)
  int8_t* dnb = (int8_t*)(ws + 25165824);   // 16 MB frag-major (16 cb x 64 t)
  ushort* hid = (ushort*)(ws + 41943040);   // 64 MB [4096][8192] bf16
  int8_t* hq  = (int8_t*)(ws + 109051904);  // 32 MB [4096][8192]
  float*  sx  = (float*)(ws + 142606336);   // 16 KB
  float*  sh  = (float*)(ws + 142622720);   // 16 KB

  quantx_kernel<<<M_TOK, 256, 0, stream>>>(x, xq, sx);
  // up: R=8192 rows, Kd=2048 -> 64 cb x 16 t; dn: R=2048, Kd=8192 -> 16 cb x 64 t
  signfrag_kernel<<<(DH / 128) * (DM / 128), 256, 0, stream>>>(upw, upb, DM, DM / 128);
  signfrag_kernel<<<(DM / 128) * (DH / 128), 256, 0, stream>>>(dnw, dnb, DH, DH / 128);

  // GEMM1: hid = relu((xq @ sign(up)^T) * sx * ups) -> bf16. grid 32x64=2048.
  gemm_bd_kernel<0><<<(M_TOK / 128) * (DH / 128), 256, 0, stream>>>(
      xq, upb, (void*)hid, sx, ups, nullptr, M_TOK, DH, DM);
  // quantize hidden per-row -> i8 + sh
  quanth_kernel<<<M_TOK, 256, 0, stream>>>(hid, hq, sh);
  // GEMM2: out = (hq @ sign(dn)^T) * sh * dns * osc -> f32. grid 32x16=512.
  gemm_bd_kernel<1><<<(M_TOK / 128) * (DM / 128), 256, 0, stream>>>(
      hq, dnb, out, sh, dns, osc, M_TOK, DM, DH);
}

// Round 9
// 174.155 us; speedup vs baseline: 1.3147x; 1.3147x over previous
//
#include <hip/hip_runtime.h>
#include <stdint.h>

// TriXTile: out = (relu((x @ sign(up_w)^T) * up_scale) @ sign(down_w)^T) * down_scale * out_scale
// Round 9: revert to r6's two proven GEMM kernels (post-timing-stable).
// Changes vs r6, all race-free per-thread arithmetic only:
//  - GEMM1 epilogue emits hq i8 = clamp(rint(relu(acc*ups)/64),0,127) directly
//    (fixed-shift quant; hidden scale = 64*sx[row] known without reduction)
//    -> quanth kernel + bf16 hid buffer deleted.
//  - GEMM2 epilogue scale folded: out = acc * sx[row]*64 * dns * osc.
//  - prepass merged into one partitioned kernel.

#define M_TOK 4096
#define DM 2048
#define DH 8192

typedef __attribute__((ext_vector_type(4))) int i32x4;

#define GLD16(g, l)                                                     \
  __builtin_amdgcn_global_load_lds(                                     \
      (const __attribute__((address_space(1))) void*)(g),               \
      (__attribute__((address_space(3))) void*)(l), 16, 0, 0)

#define FENCE() asm volatile("" ::: "memory")

// ---- merged prepass ----
// blocks [0,4096): quantize x row -> xq i8 + sx[row]
// blocks [4096,6144): sign(up_w) -> i8 ; blocks [6144,8192): sign(dn_w) -> i8
__global__ __launch_bounds__(256) void prep_kernel(
    const float* __restrict__ x, int8_t* __restrict__ xq,
    float* __restrict__ sx, const float* __restrict__ upw,
    int8_t* __restrict__ upq, const float* __restrict__ dnw,
    int8_t* __restrict__ dnq) {
  const int bid = blockIdx.x;
  const int tid = threadIdx.x;
  if (bid < 4096) {
    const int row = bid;
    const float4* xr = (const float4*)(x + (size_t)row * 2048);
    float4 a = xr[tid * 2], b = xr[tid * 2 + 1];
    float m = fmaxf(fmaxf(fmaxf(fabsf(a.x), fabsf(a.y)), fmaxf(fabsf(a.z), fabsf(a.w))),
                    fmaxf(fmaxf(fabsf(b.x), fabsf(b.y)), fmaxf(fabsf(b.z), fabsf(b.w))));
#pragma unroll
    for (int off = 32; off >= 1; off >>= 1) m = fmaxf(m, __shfl_xor(m, off));
    __shared__ float red[4];
    if ((tid & 63) == 0) red[tid >> 6] = m;
    __syncthreads();
    m = fmaxf(fmaxf(red[0], red[1]), fmaxf(red[2], red[3]));
    const float inv = m > 0.f ? 127.f / m : 0.f;
    if (tid == 0) sx[row] = m > 0.f ? m / 127.f : 0.f;
    auto q8 = [&](float v) -> uint32_t {
      float q = rintf(v * inv);
      q = fminf(fmaxf(q, -127.f), 127.f);
      return (uint32_t)(uint8_t)(int8_t)(int)q;
    };
    uint32_t w0 = q8(a.x) | (q8(a.y) << 8) | (q8(a.z) << 16) | (q8(a.w) << 24);
    uint32_t w1 = q8(b.x) | (q8(b.y) << 8) | (q8(b.z) << 16) | (q8(b.w) << 24);
    uint32_t* o = (uint32_t*)(xq + (size_t)row * 2048);
    o[tid * 2] = w0;
    o[tid * 2 + 1] = w1;
  } else {
    const bool is_up = bid < 6144;
    const float* __restrict__ W = is_up ? upw : dnw;
    int8_t* __restrict__ Q = is_up ? upq : dnq;
    const int vb = bid - (is_up ? 4096 : 6144);
    const int n4 = (DH * DM) / 4;
    const int stride = 2048 * 256;
    auto s8 = [](float v) -> uint32_t {
      int s = (v > 0.f) - (v < 0.f);
      return (uint32_t)(uint8_t)(int8_t)s;
    };
    for (int i = vb * 256 + tid; i < n4; i += stride) {
      float4 v = ((const float4*)W)[i];
      ((uint32_t*)Q)[i] = s8(v.x) | (s8(v.y) << 8) | (s8(v.z) << 16) | (s8(v.w) << 24);
    }
  }
}

// ---------------- GEMM1: 256x256 i8, v5 2-barrier schedule (r6 binary) -------
// hq[M,N] = clamp(rint(relu((xq @ upq^T) * ups[col]) / 64), 0, 127) -> i8.
// K bytes = 2048, BK=128B, nt=16. 512 thr, 8 waves 2Mx4N, 128x64/wave.
__global__ __launch_bounds__(512, 2) void gemm1_i8_kernel(
    const int8_t* __restrict__ A, const int8_t* __restrict__ B,
    int8_t* __restrict__ C, const float* __restrict__ ups,
    int M, int N, int K) {
  constexpr int TILEB = 256 * 128;      // 32768
  constexpr int BUFB = 2 * TILEB;       // 65536
  extern __shared__ char smem[];

  const int nbn = N >> 8;
  const int bid = blockIdx.x;
  const int cpx = gridDim.x >> 3;
  const int swz = (bid & 7) * cpx + (bid >> 3);
  const int bm = swz / nbn, bn = swz % nbn;

  const int tid = threadIdx.x;
  const int lane = tid & 63;
  const int wv = tid >> 6;
  const int wm = wv >> 2, wn = wv & 3;  // 2 x 4 waves, 128x64 each
  const int lr = lane & 15, lg = lane >> 4;

  const int srow = tid >> 3;
  const int scolB = ((tid & 7) ^ (srow & 7)) << 4;   // byte offset, pre-swizzled
  const int8_t* aS = A + (size_t)(bm * 256 + srow) * K + scolB;
  const int8_t* bS = B + (size_t)(bn * 256 + srow) * K + scolB;
  const int ldsl = wv * 1024;

  auto STAGE = [&](int t, int u) {
    char* dst = smem + (t & 1) * BUFB + u * 8192 + ldsl;
    const int8_t* src = (u < 4) ? aS + (size_t)(u * 64) * K + (size_t)t * 128
                                : bS + (size_t)((u - 4) * 64) * K + (size_t)t * 128;
    GLD16(src, dst);
  };

  const int nt = K >> 7;
  i32x4 acc[8][4] = {};

#pragma unroll
  for (int u = 0; u < 8; ++u) STAGE(0, u);
  if (nt > 1) {
    STAGE(1, 0); STAGE(1, 2); STAGE(1, 4); STAGE(1, 5);
    asm volatile("s_waitcnt vmcnt(4)" ::: "memory");
  } else {
    asm volatile("s_waitcnt vmcnt(0)" ::: "memory");
  }
  __builtin_amdgcn_s_barrier();

  const int xorv = (lr & 7) << 4;
  const int k0 = (lg << 4) ^ xorv;
  const int k1 = (64 + (lg << 4)) ^ xorv;
  const int abase = (wm * 128 + lr) * 128;
  const int bbase = TILEB + (wn * 64 + lr) * 128;

#define MFMA_G(Q, p, q, r, s)                                                \
  __builtin_amdgcn_s_setprio(1);                                             \
  _Pragma("unroll") for (int fc = 0; fc < 4; ++fc)                           \
      acc[2*(Q)][fc] = __builtin_amdgcn_mfma_i32_16x16x64_i8(                \
          p, b0[fc], acc[2*(Q)][fc], 0, 0, 0);                               \
  _Pragma("unroll") for (int fc = 0; fc < 4; ++fc)                           \
      acc[2*(Q)+1][fc] = __builtin_amdgcn_mfma_i32_16x16x64_i8(              \
          r, b0[fc], acc[2*(Q)+1][fc], 0, 0, 0);                             \
  _Pragma("unroll") for (int fc = 0; fc < 4; ++fc)                           \
      acc[2*(Q)][fc] = __builtin_amdgcn_mfma_i32_16x16x64_i8(                \
          q, b1[fc], acc[2*(Q)][fc], 0, 0, 0);                               \
  _Pragma("unroll") for (int fc = 0; fc < 4; ++fc)                           \
      acc[2*(Q)+1][fc] = __builtin_amdgcn_mfma_i32_16x16x64_i8(              \
          s, b1[fc], acc[2*(Q)+1][fc], 0, 0, 0);                             \
  __builtin_amdgcn_s_setprio(0);

#define WAITL(n)                                               \
  asm volatile("s_waitcnt lgkmcnt(" #n ")" ::: "memory");      \
  __builtin_amdgcn_sched_barrier(0);

  for (int t = 0; t < nt; ++t) {
    const char* bufc = smem + (t & 1) * BUFB;
    const char* bA = bufc + abase;
    const char* bB = bufc + bbase;
    i32x4 b0[4], b1[4];
    i32x4 p0, p1, p2, p3, q0, q1, q2, q3;

    p0 = *(const i32x4*)(bA + 0 * 2048 + k0);
    p1 = *(const i32x4*)(bA + 0 * 2048 + k1);
    p2 = *(const i32x4*)(bA + 1 * 2048 + k0);
    p3 = *(const i32x4*)(bA + 1 * 2048 + k1);
#pragma unroll
    for (int fc = 0; fc < 4; ++fc) {
      b0[fc] = *(const i32x4*)(bB + fc * 2048 + k0);
      b1[fc] = *(const i32x4*)(bB + fc * 2048 + k1);
    }
    FENCE();
    q0 = *(const i32x4*)(bA + 2 * 2048 + k0);
    q1 = *(const i32x4*)(bA + 2 * 2048 + k1);
    q2 = *(const i32x4*)(bA + 3 * 2048 + k0);
    q3 = *(const i32x4*)(bA + 3 * 2048 + k1);
    FENCE();
    if (t + 1 < nt) { STAGE(t + 1, 6); STAGE(t + 1, 7);
                      STAGE(t + 1, 1); STAGE(t + 1, 3); }
    WAITL(4);
    MFMA_G(0, p0, p1, p2, p3);
    p0 = *(const i32x4*)(bA + 4 * 2048 + k0);
    p1 = *(const i32x4*)(bA + 4 * 2048 + k1);
    p2 = *(const i32x4*)(bA + 5 * 2048 + k0);
    p3 = *(const i32x4*)(bA + 5 * 2048 + k1);
    FENCE();
    WAITL(4);
    MFMA_G(1, q0, q1, q2, q3);
    q0 = *(const i32x4*)(bA + 6 * 2048 + k0);
    q1 = *(const i32x4*)(bA + 6 * 2048 + k1);
    q2 = *(const i32x4*)(bA + 7 * 2048 + k0);
    q3 = *(const i32x4*)(bA + 7 * 2048 + k1);
    FENCE();
    WAITL(4);
    MFMA_G(2, p0, p1, p2, p3);
    WAITL(0);
    MFMA_G(3, q0, q1, q2, q3);

    __builtin_amdgcn_s_barrier();   // B1: all reads of current buffer done
    if (t + 2 < nt) { STAGE(t + 2, 0); STAGE(t + 2, 2);
                      STAGE(t + 2, 4); STAGE(t + 2, 5); }
    if (t + 2 < nt) {
      asm volatile("s_waitcnt vmcnt(4)" ::: "memory");
    } else {
      asm volatile("s_waitcnt vmcnt(0)" ::: "memory");
    }
    __builtin_amdgcn_s_barrier();   // B2: tile t+1 published
  }
#undef MFMA_G
#undef WAITL

  // Epilogue: hq = clamp(rint(relu(acc * ups[col]) / 64), 0, 127) -> i8
  float uc[4];
#pragma unroll
  for (int fc = 0; fc < 4; ++fc)
    uc[fc] = ups[bn * 256 + wn * 64 + fc * 16 + lr] * 0.015625f;
#pragma unroll
  for (int fr = 0; fr < 8; ++fr) {
    int gr = bm * 256 + wm * 128 + fr * 16 + lg * 4;
#pragma unroll
    for (int fc = 0; fc < 4; ++fc) {
      int gcol = bn * 256 + wn * 64 + fc * 16 + lr;
#pragma unroll
      for (int r = 0; r < 4; ++r) {
        float q = rintf(fmaxf((float)acc[fr][fc][r] * uc[fc], 0.f));
        q = fminf(q, 127.f);
        C[(size_t)(gr + r) * N + gcol] = (int8_t)(int)q;
      }
    }
  }
}

// ---------------- GEMM2: 256x128 i8, 3-buffer schedule (r6 binary) ----------
// out[M,N] = (hq @ dnq^T) * sx[row]*64 * dns[col] * osc -> f32. nt=64.
__global__ __launch_bounds__(512, 2) void gemm2_i8_kernel(
    const int8_t* __restrict__ A, const int8_t* __restrict__ B,
    float* __restrict__ C, const float* __restrict__ sx,
    const float* __restrict__ dns, const float* __restrict__ oscale,
    int M, int N, int K) {
  constexpr int ABYTES = 256 * 128;     // 32768
  constexpr int BBYTES = 128 * 128;     // 16384
  constexpr int BUFB = ABYTES + BBYTES; // 49152
  extern __shared__ char smem[];

  const int nbn = N >> 7;
  const int bid = blockIdx.x;
  const int cpx = gridDim.x >> 3;
  const int swz = (bid & 7) * cpx + (bid >> 3);
  const int bm = swz / nbn, bn = swz % nbn;

  const int tid = threadIdx.x;
  const int lane = tid & 63;
  const int wv = tid >> 6;
  const int wm = wv >> 1, wn = wv & 1;  // 4 x 2 waves, 64x64 each
  const int lr = lane & 15, lg = lane >> 4;

  const int srow = tid >> 3;
  const int scolB = ((tid & 7) ^ (srow & 7)) << 4;
  const int8_t* aS = A + (size_t)(bm * 256 + srow) * K + scolB;
  const int8_t* bS = B + (size_t)(bn * 128 + srow) * K + scolB;
  const int ldsl = wv * 1024;

  i32x4 acc[4][4] = {};
  const int nt = K >> 7;

  auto STAGE = [&](int t, int q) {
    char* dA = smem + q * BUFB;
    char* dB = dA + ABYTES;
    const int8_t* a0 = aS + (size_t)t * 128;
    const int8_t* b0 = bS + (size_t)t * 128;
#pragma unroll
    for (int a = 0; a < 4; ++a)
      GLD16(a0 + (size_t)(a * 64) * K, dA + a * 8192 + ldsl);
#pragma unroll
    for (int b = 0; b < 2; ++b)
      GLD16(b0 + (size_t)(b * 64) * K, dB + b * 8192 + ldsl);
  };

  STAGE(0, 0);
  STAGE(1, 1);
  asm volatile("s_waitcnt vmcnt(6)" ::: "memory");
  __builtin_amdgcn_s_barrier();

  const int xorv = (lr & 7) << 4;
  int cur = 0;
  for (int t = 0; t < nt; ++t) {
    int nx = cur + 2; nx = (nx >= 3) ? nx - 3 : nx;
    if (t + 2 < nt) STAGE(t + 2, nx);

    const char* cA = smem + cur * BUFB;
    const char* cB = cA + ABYTES;
    i32x4 af[2][4], bfr[2][4];
#pragma unroll
    for (int ks = 0; ks < 2; ++ks) {
      int ko = ((ks << 6) + (lg << 4)) ^ xorv;
#pragma unroll
      for (int i = 0; i < 4; ++i)
        af[ks][i] = *(const i32x4*)(cA + ((wm * 64 + i * 16 + lr) << 7) + ko);
#pragma unroll
      for (int j = 0; j < 4; ++j)
        bfr[ks][j] = *(const i32x4*)(cB + ((wn * 64 + j * 16 + lr) << 7) + ko);
    }

    __builtin_amdgcn_s_setprio(1);
#pragma unroll
    for (int ks = 0; ks < 2; ++ks)
#pragma unroll
      for (int i = 0; i < 4; ++i)
#pragma unroll
        for (int j = 0; j < 4; ++j)
          acc[i][j] = __builtin_amdgcn_mfma_i32_16x16x64_i8(
              af[ks][i], bfr[ks][j], acc[i][j], 0, 0, 0);
    __builtin_amdgcn_s_setprio(0);

    if (t + 2 < nt) {
      asm volatile("s_waitcnt vmcnt(6)" ::: "memory");
    } else if (t + 1 < nt) {
      asm volatile("s_waitcnt vmcnt(0)" ::: "memory");
    }
    __builtin_amdgcn_s_barrier();
    cur = cur + 1; if (cur == 3) cur = 0;
  }

  // Epilogue: out = acc * (sx[row]*64) * dns[col] * osc -> f32
  float osc_v = oscale[0] * 64.f;
  float dc[4];
#pragma unroll
  for (int j = 0; j < 4; ++j)
    dc[j] = dns[bn * 128 + wn * 64 + j * 16 + lr] * osc_v;
#pragma unroll
  for (int i = 0; i < 4; ++i) {
    int gr = bm * 256 + wm * 64 + i * 16 + lg * 4;
    float4 shv = *(const float4*)(sx + gr);
#pragma unroll
    for (int j = 0; j < 4; ++j) {
      int gcol = bn * 128 + wn * 64 + j * 16 + lr;
      C[(size_t)(gr + 0) * N + gcol] = (float)acc[i][j][0] * shv.x * dc[j];
      C[(size_t)(gr + 1) * N + gcol] = (float)acc[i][j][1] * shv.y * dc[j];
      C[(size_t)(gr + 2) * N + gcol] = (float)acc[i][j][2] * shv.z * dc[j];
      C[(size_t)(gr + 3) * N + gcol] = (float)acc[i][j][3] * shv.w * dc[j];
    }
  }
}

extern "C" void kernel_launch(void* const* d_in, const int* in_sizes, int n_in,
                              void* d_out, int out_size, void* d_ws,
                              size_t ws_size, hipStream_t stream) {
  const float* x   = (const float*)d_in[0];
  const float* upw = (const float*)d_in[1];
  const float* dnw = (const float*)d_in[2];
  const float* ups = (const float*)d_in[3];
  const float* dns = (const float*)d_in[4];
  const float* osc = (const float*)d_in[5];
  float* out = (float*)d_out;

  char* ws = (char*)d_ws;
  int8_t* xq  = (int8_t*)(ws);              //  8 MB [4096][2048]
  int8_t* upq = (int8_t*)(ws + 8388608);    // 16 MB [8192][2048]
  int8_t* dnq = (int8_t*)(ws + 25165824);   // 16 MB [2048][8192]
  int8_t* hq  = (int8_t*)(ws + 41943040);   // 32 MB [4096][8192]
  float*  sx  = (float*)(ws + 75497472);    // 16 KB [4096]

  prep_kernel<<<8192, 256, 0, stream>>>(x, xq, sx, upw, upq, dnw, dnq);

  const int smem1 = 131072;  // 2 x 64 KB
  const int smem2 = 147456;  // 3 x 48 KB
  (void)hipFuncSetAttribute(reinterpret_cast<const void*>(gemm1_i8_kernel),
                            hipFuncAttributeMaxDynamicSharedMemorySize, smem1);
  (void)hipFuncSetAttribute(reinterpret_cast<const void*>(gemm2_i8_kernel),
                            hipFuncAttributeMaxDynamicSharedMemorySize, smem2);

  // GEMM1: hq = quant64(relu((xq @ upq^T) * ups)) -> i8. grid 16*32 = 512.
  gemm1_i8_kernel<<<(M_TOK / 256) * (DH / 256), 512, smem1, stream>>>(
      xq, upq, hq, ups, M_TOK, DH, DM);
  // GEMM2: out = (hq @ dnq^T) * sx*64 * dns * osc -> f32. grid 16*16 = 256.
  gemm2_i8_kernel<<<(M_TOK / 256) * (DM / 128), 512, smem2, stream>>>(
      hq, dnq, out, sx, dns, osc, M_TOK, DM, DH);
}

// Round 10
// 172.772 us; speedup vs baseline: 1.3252x; 1.0080x over previous
//
#include <hip/hip_runtime.h>
#include <stdint.h>

// TriXTile: out = (relu((x @ sign(up_w)^T) * up_scale) @ sign(down_w)^T) * down_scale * out_scale
// Round 10: GEMM1 keeps r9's proven 2-barrier + EARLY/LATE staging + vmcnt(4)
// ledger, but drops the intra-tile WAITL/FENCE serialization (compiler now
// schedules ds_reads/MFMAs freely, as in the LDS-saturating GEMM2 structure).
// sched_barrier(0) belts around B1/B2 pin ds_read issue inside the safe window.
// GEMM2 and prep byte-identical to r9.

#define M_TOK 4096
#define DM 2048
#define DH 8192

typedef __attribute__((ext_vector_type(4))) int i32x4;

#define GLD16(g, l)                                                     \
  __builtin_amdgcn_global_load_lds(                                     \
      (const __attribute__((address_space(1))) void*)(g),               \
      (__attribute__((address_space(3))) void*)(l), 16, 0, 0)

// ---- merged prepass (r9 verbatim) ----
__global__ __launch_bounds__(256) void prep_kernel(
    const float* __restrict__ x, int8_t* __restrict__ xq,
    float* __restrict__ sx, const float* __restrict__ upw,
    int8_t* __restrict__ upq, const float* __restrict__ dnw,
    int8_t* __restrict__ dnq) {
  const int bid = blockIdx.x;
  const int tid = threadIdx.x;
  if (bid < 4096) {
    const int row = bid;
    const float4* xr = (const float4*)(x + (size_t)row * 2048);
    float4 a = xr[tid * 2], b = xr[tid * 2 + 1];
    float m = fmaxf(fmaxf(fmaxf(fabsf(a.x), fabsf(a.y)), fmaxf(fabsf(a.z), fabsf(a.w))),
                    fmaxf(fmaxf(fabsf(b.x), fabsf(b.y)), fmaxf(fabsf(b.z), fabsf(b.w))));
#pragma unroll
    for (int off = 32; off >= 1; off >>= 1) m = fmaxf(m, __shfl_xor(m, off));
    __shared__ float red[4];
    if ((tid & 63) == 0) red[tid >> 6] = m;
    __syncthreads();
    m = fmaxf(fmaxf(red[0], red[1]), fmaxf(red[2], red[3]));
    const float inv = m > 0.f ? 127.f / m : 0.f;
    if (tid == 0) sx[row] = m > 0.f ? m / 127.f : 0.f;
    auto q8 = [&](float v) -> uint32_t {
      float q = rintf(v * inv);
      q = fminf(fmaxf(q, -127.f), 127.f);
      return (uint32_t)(uint8_t)(int8_t)(int)q;
    };
    uint32_t w0 = q8(a.x) | (q8(a.y) << 8) | (q8(a.z) << 16) | (q8(a.w) << 24);
    uint32_t w1 = q8(b.x) | (q8(b.y) << 8) | (q8(b.z) << 16) | (q8(b.w) << 24);
    uint32_t* o = (uint32_t*)(xq + (size_t)row * 2048);
    o[tid * 2] = w0;
    o[tid * 2 + 1] = w1;
  } else {
    const bool is_up = bid < 6144;
    const float* __restrict__ W = is_up ? upw : dnw;
    int8_t* __restrict__ Q = is_up ? upq : dnq;
    const int vb = bid - (is_up ? 4096 : 6144);
    const int n4 = (DH * DM) / 4;
    const int stride = 2048 * 256;
    auto s8 = [](float v) -> uint32_t {
      int s = (v > 0.f) - (v < 0.f);
      return (uint32_t)(uint8_t)(int8_t)s;
    };
    for (int i = vb * 256 + tid; i < n4; i += stride) {
      float4 v = ((const float4*)W)[i];
      ((uint32_t*)Q)[i] = s8(v.x) | (s8(v.y) << 8) | (s8(v.z) << 16) | (s8(v.w) << 24);
    }
  }
}

// ---------------- GEMM1: 256x256 i8, 2-barrier skeleton, relaxed inner ------
// hq[M,N] = clamp(rint(relu((xq @ upq^T) * ups[col]) / 64), 0, 127) -> i8.
// K=2048B, BK=128B, nt=16. 512 thr, 8 waves 2Mx4N, 128x64/wave.
// Barrier/stage/vmcnt skeleton IDENTICAL to r9 (proven): EARLY {6,7,1,3}->
// other buf mid-tile; B1; LATE {0,2,4,5}->cur buf; vmcnt(4); B2.
// Intra-tile: no explicit lgkm waits/fences -- compiler schedules (GEMM2-style).
// sched_barrier(0) before B1 pins ds_read issue above the LATE overwrites.
__global__ __launch_bounds__(512, 2) void gemm1_i8_kernel(
    const int8_t* __restrict__ A, const int8_t* __restrict__ B,
    int8_t* __restrict__ C, const float* __restrict__ ups,
    int M, int N, int K) {
  constexpr int TILEB = 256 * 128;      // 32768
  constexpr int BUFB = 2 * TILEB;       // 65536
  extern __shared__ char smem[];

  const int nbn = N >> 8;
  const int bid = blockIdx.x;
  const int cpx = gridDim.x >> 3;
  const int swz = (bid & 7) * cpx + (bid >> 3);
  const int bm = swz / nbn, bn = swz % nbn;

  const int tid = threadIdx.x;
  const int lane = tid & 63;
  const int wv = tid >> 6;
  const int wm = wv >> 2, wn = wv & 3;  // 2 x 4 waves, 128x64 each
  const int lr = lane & 15, lg = lane >> 4;

  const int srow = tid >> 3;
  const int scolB = ((tid & 7) ^ (srow & 7)) << 4;   // pre-swizzled src col
  const int8_t* aS = A + (size_t)(bm * 256 + srow) * K + scolB;
  const int8_t* bS = B + (size_t)(bn * 256 + srow) * K + scolB;
  const int ldsl = wv * 1024;

  auto STAGE = [&](int t, int u) {
    char* dst = smem + (t & 1) * BUFB + u * 8192 + ldsl;
    const int8_t* src = (u < 4) ? aS + (size_t)(u * 64) * K + (size_t)t * 128
                                : bS + (size_t)((u - 4) * 64) * K + (size_t)t * 128;
    GLD16(src, dst);
  };

  const int nt = K >> 7;
  i32x4 acc[8][4] = {};

  // Prologue: tile0 all 8 units + LATE(1); vmcnt(4) retires tile0.
#pragma unroll
  for (int u = 0; u < 8; ++u) STAGE(0, u);
  if (nt > 1) {
    STAGE(1, 0); STAGE(1, 2); STAGE(1, 4); STAGE(1, 5);
    asm volatile("s_waitcnt vmcnt(4)" ::: "memory");
  } else {
    asm volatile("s_waitcnt vmcnt(0)" ::: "memory");
  }
  __builtin_amdgcn_s_barrier();

  const int xorv = (lr & 7) << 4;
  const int k0 = (lg << 4) ^ xorv;
  const int k1 = (64 + (lg << 4)) ^ xorv;
  const int abase = (wm * 128 + lr) * 128;
  const int bbase = TILEB + (wn * 64 + lr) * 128;

  for (int t = 0; t < nt; ++t) {
    const char* bufc = smem + (t & 1) * BUFB;
    const char* bA = bufc + abase;
    const char* bB = bufc + bbase;

    i32x4 b0[4], b1[4];
#pragma unroll
    for (int fc = 0; fc < 4; ++fc) {
      b0[fc] = *(const i32x4*)(bB + fc * 2048 + k0);
      b1[fc] = *(const i32x4*)(bB + fc * 2048 + k1);
    }
    // EARLY stages: tile t+1 units {6,7,1,3} -> other buffer (readers done
    // before B2(t-1), which we passed).
    if (t + 1 < nt) { STAGE(t + 1, 6); STAGE(t + 1, 7);
                      STAGE(t + 1, 1); STAGE(t + 1, 3); }

#pragma unroll
    for (int qd = 0; qd < 4; ++qd) {
      i32x4 a0 = *(const i32x4*)(bA + (2 * qd) * 2048 + k0);
      i32x4 a1 = *(const i32x4*)(bA + (2 * qd) * 2048 + k1);
      i32x4 a2 = *(const i32x4*)(bA + (2 * qd + 1) * 2048 + k0);
      i32x4 a3 = *(const i32x4*)(bA + (2 * qd + 1) * 2048 + k1);
      __builtin_amdgcn_s_setprio(1);
#pragma unroll
      for (int fc = 0; fc < 4; ++fc)
        acc[2 * qd][fc] = __builtin_amdgcn_mfma_i32_16x16x64_i8(
            a0, b0[fc], acc[2 * qd][fc], 0, 0, 0);
#pragma unroll
      for (int fc = 0; fc < 4; ++fc)
        acc[2 * qd + 1][fc] = __builtin_amdgcn_mfma_i32_16x16x64_i8(
            a2, b0[fc], acc[2 * qd + 1][fc], 0, 0, 0);
#pragma unroll
      for (int fc = 0; fc < 4; ++fc)
        acc[2 * qd][fc] = __builtin_amdgcn_mfma_i32_16x16x64_i8(
            a1, b1[fc], acc[2 * qd][fc], 0, 0, 0);
#pragma unroll
      for (int fc = 0; fc < 4; ++fc)
        acc[2 * qd + 1][fc] = __builtin_amdgcn_mfma_i32_16x16x64_i8(
            a3, b1[fc], acc[2 * qd + 1][fc], 0, 0, 0);
      __builtin_amdgcn_s_setprio(0);
    }

    // Pin every ds_read issue above B1 (no read may slip into the LATE
    // overwrite window), then B1: all waves done reading current buffer.
    __builtin_amdgcn_sched_barrier(0);
    __builtin_amdgcn_s_barrier();
    // LATE stages: tile t+2 units {0,2,4,5} -> current buffer (now dead).
    if (t + 2 < nt) { STAGE(t + 2, 0); STAGE(t + 2, 2);
                      STAGE(t + 2, 4); STAGE(t + 2, 5); }
    // Ledger: L(t+1)[4] + E(t+1)[4] + L(t+2)[4] = 12; retire tile t+1.
    if (t + 2 < nt) {
      asm volatile("s_waitcnt vmcnt(4)" ::: "memory");
    } else {
      asm volatile("s_waitcnt vmcnt(0)" ::: "memory");
    }
    __builtin_amdgcn_s_barrier();   // B2: tile t+1 published
    __builtin_amdgcn_sched_barrier(0);
  }

  // Epilogue: hq = clamp(rint(relu(acc * ups[col]) / 64), 0, 127) -> i8
  float uc[4];
#pragma unroll
  for (int fc = 0; fc < 4; ++fc)
    uc[fc] = ups[bn * 256 + wn * 64 + fc * 16 + lr] * 0.015625f;
#pragma unroll
  for (int fr = 0; fr < 8; ++fr) {
    int gr = bm * 256 + wm * 128 + fr * 16 + lg * 4;
#pragma unroll
    for (int fc = 0; fc < 4; ++fc) {
      int gcol = bn * 256 + wn * 64 + fc * 16 + lr;
#pragma unroll
      for (int r = 0; r < 4; ++r) {
        float q = rintf(fmaxf((float)acc[fr][fc][r] * uc[fc], 0.f));
        q = fminf(q, 127.f);
        C[(size_t)(gr + r) * N + gcol] = (int8_t)(int)q;
      }
    }
  }
}

// ---------------- GEMM2: 256x128 i8, 3-buffer schedule (r9 verbatim) --------
__global__ __launch_bounds__(512, 2) void gemm2_i8_kernel(
    const int8_t* __restrict__ A, const int8_t* __restrict__ B,
    float* __restrict__ C, const float* __restrict__ sx,
    const float* __restrict__ dns, const float* __restrict__ oscale,
    int M, int N, int K) {
  constexpr int ABYTES = 256 * 128;     // 32768
  constexpr int BBYTES = 128 * 128;     // 16384
  constexpr int BUFB = ABYTES + BBYTES; // 49152
  extern __shared__ char smem[];

  const int nbn = N >> 7;
  const int bid = blockIdx.x;
  const int cpx = gridDim.x >> 3;
  const int swz = (bid & 7) * cpx + (bid >> 3);
  const int bm = swz / nbn, bn = swz % nbn;

  const int tid = threadIdx.x;
  const int lane = tid & 63;
  const int wv = tid >> 6;
  const int wm = wv >> 1, wn = wv & 1;  // 4 x 2 waves, 64x64 each
  const int lr = lane & 15, lg = lane >> 4;

  const int srow = tid >> 3;
  const int scolB = ((tid & 7) ^ (srow & 7)) << 4;
  const int8_t* aS = A + (size_t)(bm * 256 + srow) * K + scolB;
  const int8_t* bS = B + (size_t)(bn * 128 + srow) * K + scolB;
  const int ldsl = wv * 1024;

  i32x4 acc[4][4] = {};
  const int nt = K >> 7;

  auto STAGE = [&](int t, int q) {
    char* dA = smem + q * BUFB;
    char* dB = dA + ABYTES;
    const int8_t* a0 = aS + (size_t)t * 128;
    const int8_t* b0 = bS + (size_t)t * 128;
#pragma unroll
    for (int a = 0; a < 4; ++a)
      GLD16(a0 + (size_t)(a * 64) * K, dA + a * 8192 + ldsl);
#pragma unroll
    for (int b = 0; b < 2; ++b)
      GLD16(b0 + (size_t)(b * 64) * K, dB + b * 8192 + ldsl);
  };

  STAGE(0, 0);
  STAGE(1, 1);
  asm volatile("s_waitcnt vmcnt(6)" ::: "memory");
  __builtin_amdgcn_s_barrier();

  const int xorv = (lr & 7) << 4;
  int cur = 0;
  for (int t = 0; t < nt; ++t) {
    int nx = cur + 2; nx = (nx >= 3) ? nx - 3 : nx;
    if (t + 2 < nt) STAGE(t + 2, nx);

    const char* cA = smem + cur * BUFB;
    const char* cB = cA + ABYTES;
    i32x4 af[2][4], bfr[2][4];
#pragma unroll
    for (int ks = 0; ks < 2; ++ks) {
      int ko = ((ks << 6) + (lg << 4)) ^ xorv;
#pragma unroll
      for (int i = 0; i < 4; ++i)
        af[ks][i] = *(const i32x4*)(cA + ((wm * 64 + i * 16 + lr) << 7) + ko);
#pragma unroll
      for (int j = 0; j < 4; ++j)
        bfr[ks][j] = *(const i32x4*)(cB + ((wn * 64 + j * 16 + lr) << 7) + ko);
    }

    __builtin_amdgcn_s_setprio(1);
#pragma unroll
    for (int ks = 0; ks < 2; ++ks)
#pragma unroll
      for (int i = 0; i < 4; ++i)
#pragma unroll
        for (int j = 0; j < 4; ++j)
          acc[i][j] = __builtin_amdgcn_mfma_i32_16x16x64_i8(
              af[ks][i], bfr[ks][j], acc[i][j], 0, 0, 0);
    __builtin_amdgcn_s_setprio(0);

    if (t + 2 < nt) {
      asm volatile("s_waitcnt vmcnt(6)" ::: "memory");
    } else if (t + 1 < nt) {
      asm volatile("s_waitcnt vmcnt(0)" ::: "memory");
    }
    __builtin_amdgcn_s_barrier();
    cur = cur + 1; if (cur == 3) cur = 0;
  }

  float osc_v = oscale[0] * 64.f;
  float dc[4];
#pragma unroll
  for (int j = 0; j < 4; ++j)
    dc[j] = dns[bn * 128 + wn * 64 + j * 16 + lr] * osc_v;
#pragma unroll
  for (int i = 0; i < 4; ++i) {
    int gr = bm * 256 + wm * 64 + i * 16 + lg * 4;
    float4 shv = *(const float4*)(sx + gr);
#pragma unroll
    for (int j = 0; j < 4; ++j) {
      int gcol = bn * 128 + wn * 64 + j * 16 + lr;
      C[(size_t)(gr + 0) * N + gcol] = (float)acc[i][j][0] * shv.x * dc[j];
      C[(size_t)(gr + 1) * N + gcol] = (float)acc[i][j][1] * shv.y * dc[j];
      C[(size_t)(gr + 2) * N + gcol] = (float)acc[i][j][2] * shv.z * dc[j];
      C[(size_t)(gr + 3) * N + gcol] = (float)acc[i][j][3] * shv.w * dc[j];
    }
  }
}

extern "C" void kernel_launch(void* const* d_in, const int* in_sizes, int n_in,
                              void* d_out, int out_size, void* d_ws,
                              size_t ws_size, hipStream_t stream) {
  const float* x   = (const float*)d_in[0];
  const float* upw = (const float*)d_in[1];
  const float* dnw = (const float*)d_in[2];
  const float* ups = (const float*)d_in[3];
  const float* dns = (const float*)d_in[4];
  const float* osc = (const float*)d_in[5];
  float* out = (float*)d_out;

  char* ws = (char*)d_ws;
  int8_t* xq  = (int8_t*)(ws);              //  8 MB [4096][2048]
  int8_t* upq = (int8_t*)(ws + 8388608);    // 16 MB [8192][2048]
  int8_t* dnq = (int8_t*)(ws + 25165824);   // 16 MB [2048][8192]
  int8_t* hq  = (int8_t*)(ws + 41943040);   // 32 MB [4096][8192]
  float*  sx  = (float*)(ws + 75497472);    // 16 KB [4096]

  prep_kernel<<<8192, 256, 0, stream>>>(x, xq, sx, upw, upq, dnw, dnq);

  const int smem1 = 131072;  // 2 x 64 KB
  const int smem2 = 147456;  // 3 x 48 KB
  (void)hipFuncSetAttribute(reinterpret_cast<const void*>(gemm1_i8_kernel),
                            hipFuncAttributeMaxDynamicSharedMemorySize, smem1);
  (void)hipFuncSetAttribute(reinterpret_cast<const void*>(gemm2_i8_kernel),
                            hipFuncAttributeMaxDynamicSharedMemorySize, smem2);

  // GEMM1: hq = quant64(relu((xq @ upq^T) * ups)) -> i8. grid 16*32 = 512.
  gemm1_i8_kernel<<<(M_TOK / 256) * (DH / 256), 512, smem1, stream>>>(
      xq, upq, hq, ups, M_TOK, DH, DM);
  // GEMM2: out = (hq @ dnq^T) * sx*64 * dns * osc -> f32. grid 16*16 = 256.
  gemm2_i8_kernel<<<(M_TOK / 256) * (DM / 128), 512, smem2, stream>>>(
      hq, dnq, out, sx, dns, osc, M_TOK, DM, DH);
}